// Round 1
// baseline (55.780 us; speedup 1.0000x reference)
//
#include <hip/hip_runtime.h>

// Problem constants
#define B_   8
#define N1_  32
#define N2_  8
#define D_   128
#define S2_  16384
#define SP_  2048
#define G_   4            // GQA group size = N1/N2
#define NSPLIT 16
#define CH   (SP_ / NSPLIT)   // 128 indices per block
#define CHW  (CH / 4)         // 32 indices per wave

// Kernel 1: per (b, n2, split) partial attention.
// Block = 256 threads = 4 waves. Wave w handles indices [w*CHW, (w+1)*CHW).
// Each wave gathers one 512B K/V row per index (float2 per lane, coalesced).
__global__ __launch_bounds__(256) void attn_part(
    const float* __restrict__ q, const float* __restrict__ key,
    const float* __restrict__ value, const int* __restrict__ sidx,
    const float* __restrict__ scale_p, float* __restrict__ ws_o,
    float2* __restrict__ ws_ml)
{
    const int blk   = blockIdx.x;
    const int split = blk & (NSPLIT - 1);
    const int pair  = blk / NSPLIT;        // b*N2 + n2
    const int n2    = pair & (N2_ - 1);
    const int tid   = threadIdx.x;
    const int lane  = tid & 63;
    const int w     = tid >> 6;            // wave id 0..3

    __shared__ float s_lds[CH][4];         // scores -> p
    __shared__ float ml[G_][2];            // per-head (max, sum)
    __shared__ float red[4][64][8];        // cross-wave PV combine

    const float scale = scale_p[0];

    // q for the 4 heads of this group, scaled; lane owns dims (2*lane, 2*lane+1)
    const float* qb = q + (size_t)(pair * G_) * D_ + lane * 2;
    float2 q2[G_];
#pragma unroll
    for (int h = 0; h < G_; ++h) {
        float2 t = *(const float2*)(qb + h * D_);
        q2[h] = make_float2(t.x * scale, t.y * scale);
    }

    // preload this wave's 32 indices into registers (lanes 32..63 duplicate)
    const int* idx_base = sidx + (size_t)pair * SP_ + split * CH + w * CHW;
    int myidx = idx_base[lane & (CHW - 1)];

    const size_t kvoff = (size_t)(pair / N2_) * ((size_t)S2_ * N2_ * D_)
                       + (size_t)n2 * D_;
    const float* kb = key   + kvoff + lane * 2;
    const float* vb = value + kvoff + lane * 2;

    // ---- Phase 1: scores ----
#pragma unroll
    for (int jj = 0; jj < CHW; ++jj) {
        int s2 = __shfl(myidx, jj);
        float2 kv = *(const float2*)(kb + (size_t)s2 * (N2_ * D_));
        float p0 = q2[0].x * kv.x + q2[0].y * kv.y;
        float p1 = q2[1].x * kv.x + q2[1].y * kv.y;
        float p2 = q2[2].x * kv.x + q2[2].y * kv.y;
        float p3 = q2[3].x * kv.x + q2[3].y * kv.y;
#pragma unroll
        for (int off = 1; off < 64; off <<= 1) {
            p0 += __shfl_xor(p0, off);
            p1 += __shfl_xor(p1, off);
            p2 += __shfl_xor(p2, off);
            p3 += __shfl_xor(p3, off);
        }
        if (lane == 0) {
            *(float4*)&s_lds[w * CHW + jj][0] = make_float4(p0, p1, p2, p3);
        }
    }
    __syncthreads();

    // ---- Softmax (split-local): wave w handles head w ----
    {
        float s0 = s_lds[lane][w];
        float s1 = s_lds[lane + 64][w];
        float mx = fmaxf(s0, s1);
#pragma unroll
        for (int off = 1; off < 64; off <<= 1)
            mx = fmaxf(mx, __shfl_xor(mx, off));
        float e0 = __expf(s0 - mx);
        float e1 = __expf(s1 - mx);
        s_lds[lane][w]      = e0;
        s_lds[lane + 64][w] = e1;
        float sm = e0 + e1;
#pragma unroll
        for (int off = 1; off < 64; off <<= 1)
            sm += __shfl_xor(sm, off);
        if (lane == 0) { ml[w][0] = mx; ml[w][1] = sm; }
    }
    __syncthreads();

    // ---- Phase 2: PV ----
    float2 a0 = make_float2(0.f, 0.f), a1 = a0, a2 = a0, a3 = a0;
#pragma unroll
    for (int jj = 0; jj < CHW; ++jj) {
        int s2 = __shfl(myidx, jj);
        float2 vv = *(const float2*)(vb + (size_t)s2 * (N2_ * D_));
        float4 p4 = *(const float4*)&s_lds[w * CHW + jj][0];  // broadcast
        a0.x += p4.x * vv.x;  a0.y += p4.x * vv.y;
        a1.x += p4.y * vv.x;  a1.y += p4.y * vv.y;
        a2.x += p4.z * vv.x;  a2.y += p4.z * vv.y;
        a3.x += p4.w * vv.x;  a3.y += p4.w * vv.y;
    }

    *(float4*)&red[w][lane][0] = make_float4(a0.x, a0.y, a1.x, a1.y);
    *(float4*)&red[w][lane][4] = make_float4(a2.x, a2.y, a3.x, a3.y);
    __syncthreads();

    // thread (w, lane): head h = w, dims (2*lane, 2*lane+1) summed over waves
    float ox = 0.f, oy = 0.f;
#pragma unroll
    for (int ww = 0; ww < 4; ++ww) {
        ox += red[ww][lane][2 * w];
        oy += red[ww][lane][2 * w + 1];
    }
    float* wo = ws_o + ((size_t)(pair * G_ + w) * NSPLIT + split) * D_ + 2 * lane;
    wo[0] = ox;
    wo[1] = oy;
    if (lane == 0)
        ws_ml[(pair * G_ + w) * NSPLIT + split] = make_float2(ml[w][0], ml[w][1]);
}

// Kernel 2: combine NSPLIT partials per (b, n2). 512 threads: t -> (h = t>>7, d = t&127)
__global__ __launch_bounds__(512) void attn_comb(
    const float* __restrict__ ws_o, const float2* __restrict__ ws_ml,
    float* __restrict__ out)
{
    const int pair = blockIdx.x;
    const int tid  = threadIdx.x;

    __shared__ float2 sml[G_ * NSPLIT];
    if (tid < G_ * NSPLIT) sml[tid] = ws_ml[pair * G_ * NSPLIT + tid];
    __syncthreads();

    const int h = tid >> 7;
    const int d = tid & 127;

    float M = -1e30f;
#pragma unroll
    for (int s = 0; s < NSPLIT; ++s)
        M = fmaxf(M, sml[h * NSPLIT + s].x);

    float L = 0.f, acc = 0.f;
    const float* wo = ws_o + ((size_t)(pair * G_ + h) * NSPLIT) * D_ + d;
#pragma unroll
    for (int s = 0; s < NSPLIT; ++s) {
        float2 mlv = sml[h * NSPLIT + s];
        float wgt  = __expf(mlv.x - M);
        L   += wgt * mlv.y;
        acc += wgt * wo[(size_t)s * D_];
    }
    out[(size_t)pair * (G_ * D_) + tid] = acc / L;
}

extern "C" void kernel_launch(void* const* d_in, const int* in_sizes, int n_in,
                              void* d_out, int out_size, void* d_ws, size_t ws_size,
                              hipStream_t stream)
{
    const float* q  = (const float*)d_in[0];
    const float* k  = (const float*)d_in[1];
    const float* v  = (const float*)d_in[2];
    const int*   si = (const int*)d_in[3];
    const float* sc = (const float*)d_in[4];
    float* out = (float*)d_out;

    float*  ws_o  = (float*)d_ws;
    float2* ws_ml = (float2*)(ws_o + (size_t)B_ * N2_ * G_ * NSPLIT * D_);

    attn_part<<<B_ * N2_ * NSPLIT, 256, 0, stream>>>(q, k, v, si, sc, ws_o, ws_ml);
    attn_comb<<<B_ * N2_, 512, 0, stream>>>(ws_o, ws_ml, out);
}

// Round 2
// 46.952 us; speedup vs baseline: 1.1880x; 1.1880x over previous
//
#include <hip/hip_runtime.h>

// Problem constants
#define B_   8
#define N1_  32
#define N2_  8
#define D_   128
#define S2_  16384
#define SP_  2048
#define G_   4              // GQA group size = N1/N2
#define NSPLIT 64           // splits per (b,n2); one WAVE per split
#define CHW  (SP_ / NSPLIT) // 32 indices per wave-split
#define SPG  (NSPLIT / 4)   // split-groups per pair (4 waves/block)

// Kernel 1: per (b, n2, split) partial attention. One wave per split,
// fully independent: no __syncthreads, no LDS.
//  - K phase: per index, coalesced float2/lane row gather, 4-head dot,
//    head-interleaved butterfly reduce (7 shuffles) -> lane holds score
//    for head (lane&3) in a register.
//  - softmax entirely in registers (16-fold redundancy across head group).
//  - PV phase: lane owns (head lane&3, dims 8*(lane>>2)..+7); p is already
//    lane-local, V read with 4-way duplicated lanes (same 512B row).
__global__ __launch_bounds__(256, 4) void attn_part(
    const float* __restrict__ q, const float* __restrict__ key,
    const float* __restrict__ value, const int* __restrict__ sidx,
    const float* __restrict__ scale_p, float* __restrict__ ws_o,
    float2* __restrict__ ws_ml)
{
    const int blk   = blockIdx.x;
    const int tid   = threadIdx.x;
    const int lane  = tid & 63;
    const int w     = tid >> 6;
    const int pair  = blk / SPG;              // b*N2 + n2
    const int split = (blk % SPG) * 4 + w;    // 0..63
    const int n2    = pair & (N2_ - 1);
    const int b     = pair >> 3;

    const float scale = scale_p[0];

    // q for the 4 heads of this group, scaled; lane owns dims (2l, 2l+1)
    const float* qb = q + (size_t)(pair * G_) * D_ + (lane << 1);
    float2 q2[G_];
#pragma unroll
    for (int h = 0; h < G_; ++h) {
        float2 t = *(const float2*)(qb + h * D_);
        q2[h] = make_float2(t.x * scale, t.y * scale);
    }

    // this split's 32 indices, one per lane (upper lanes duplicate)
    const int* idx_base = sidx + (size_t)pair * SP_ + split * CHW;
    const int myidx = idx_base[lane & (CHW - 1)];

    const size_t kvbase = (size_t)b * ((size_t)S2_ * N2_ * D_) + (size_t)n2 * D_;
    const float* kb = key + kvbase + (lane << 1);

    // ---- Phase 1: scores (register-resident) ----
    float x[CHW];
#pragma unroll
    for (int jj = 0; jj < CHW; ++jj) {
        const int s2 = __shfl(myidx, jj);
        const float2 kv = *(const float2*)(kb + (size_t)s2 * (N2_ * D_));
        float p0 = q2[0].x * kv.x + q2[0].y * kv.y;
        float p1 = q2[1].x * kv.x + q2[1].y * kv.y;
        float p2 = q2[2].x * kv.x + q2[2].y * kv.y;
        float p3 = q2[3].x * kv.x + q2[3].y * kv.y;
        // head-interleaved butterfly: 7 shuffles total.
        // step 1 (xor 1): a <- head (lane&1) pair-sum of {p0,p1}
        float a  = (lane & 1) ? p1 : p0;
        float sb = (lane & 1) ? p0 : p1;
        a += __shfl_xor(sb, 1);
        float c  = (lane & 1) ? p3 : p2;
        float sd = (lane & 1) ? p2 : p3;
        c += __shfl_xor(sd, 1);
        // step 2 (xor 2): e <- head (lane&3) 4-lane-group sum
        float e  = (lane & 2) ? c : a;
        float sf = (lane & 2) ? a : c;
        e += __shfl_xor(sf, 2);
        // steps 3-6: plain butterfly; e = full 64-lane sum for head (lane&3)
        e += __shfl_xor(e, 4);
        e += __shfl_xor(e, 8);
        e += __shfl_xor(e, 16);
        e += __shfl_xor(e, 32);
        x[jj] = e;
    }

    // ---- softmax in registers (per-lane, head = lane&3) ----
    float m = x[0];
#pragma unroll
    for (int jj = 1; jj < CHW; ++jj) m = fmaxf(m, x[jj]);
    float sum = 0.f;
#pragma unroll
    for (int jj = 0; jj < CHW; ++jj) {
        x[jj] = __expf(x[jj] - m);
        sum += x[jj];
    }

    // ---- Phase 2: PV. lane -> (head lane&3, dims 8c..8c+7, c=lane>>2) ----
    const float* vb = value + kvbase + ((lane >> 2) << 3);
    float4 acc0 = make_float4(0.f, 0.f, 0.f, 0.f);
    float4 acc1 = make_float4(0.f, 0.f, 0.f, 0.f);
#pragma unroll
    for (int jj = 0; jj < CHW; ++jj) {
        const int s2 = __shfl(myidx, jj);
        const float* vr = vb + (size_t)s2 * (N2_ * D_);
        const float4 v0 = *(const float4*)(vr);
        const float4 v1 = *(const float4*)(vr + 4);
        const float p = x[jj];
        acc0.x += p * v0.x;  acc0.y += p * v0.y;
        acc0.z += p * v0.z;  acc0.w += p * v0.w;
        acc1.x += p * v1.x;  acc1.y += p * v1.y;
        acc1.z += p * v1.z;  acc1.w += p * v1.w;
    }

    // ---- write partials ----
    float* wo = ws_o + ((size_t)(pair * G_ + (lane & 3)) * NSPLIT + split) * D_
              + ((lane >> 2) << 3);
    *(float4*)(wo)     = acc0;
    *(float4*)(wo + 4) = acc1;
    if (lane < G_)
        ws_ml[((size_t)pair * G_ + lane) * NSPLIT + split] = make_float2(m, sum);
}

// Kernel 2: combine NSPLIT partials. One block per (pair, head), 128 threads
// (thread = dim). Standard log-sum-exp merge.
__global__ __launch_bounds__(128) void attn_comb(
    const float* __restrict__ ws_o, const float2* __restrict__ ws_ml,
    float* __restrict__ out)
{
    const int ph  = blockIdx.x;       // pair*G + h
    const int tid = threadIdx.x;      // dim

    __shared__ float2 sml[NSPLIT];
    if (tid < NSPLIT) sml[tid] = ws_ml[(size_t)ph * NSPLIT + tid];
    __syncthreads();

    float M = -1e30f;
#pragma unroll
    for (int s = 0; s < NSPLIT; ++s)
        M = fmaxf(M, sml[s].x);

    float L = 0.f, acc = 0.f;
    const float* wo = ws_o + (size_t)ph * NSPLIT * D_ + tid;
#pragma unroll
    for (int s = 0; s < NSPLIT; ++s) {
        const float2 mlv = sml[s];
        const float wgt  = __expf(mlv.x - M);
        L   += wgt * mlv.y;
        acc += wgt * wo[(size_t)s * D_];
    }
    out[(size_t)ph * D_ + tid] = acc / L;
}

extern "C" void kernel_launch(void* const* d_in, const int* in_sizes, int n_in,
                              void* d_out, int out_size, void* d_ws, size_t ws_size,
                              hipStream_t stream)
{
    const float* q  = (const float*)d_in[0];
    const float* k  = (const float*)d_in[1];
    const float* v  = (const float*)d_in[2];
    const int*   si = (const int*)d_in[3];
    const float* sc = (const float*)d_in[4];
    float* out = (float*)d_out;

    float*  ws_o  = (float*)d_ws;                                    // 8 MB
    float2* ws_ml = (float2*)(ws_o + (size_t)B_ * N2_ * G_ * NSPLIT * D_);

    attn_part<<<B_ * N2_ * SPG, 256, 0, stream>>>(q, k, v, si, sc, ws_o, ws_ml);
    attn_comb<<<B_ * N2_ * G_, 128, 0, stream>>>(ws_o, ws_ml, out);
}

// Round 3
// 33.999 us; speedup vs baseline: 1.6406x; 1.3810x over previous
//
#include <hip/hip_runtime.h>

// Problem constants
#define B_   8
#define N1_  32
#define N2_  8
#define D_   128
#define S2_  16384
#define SP_  2048
#define G_   4              // GQA group size = N1/N2
#define NSPLIT 64           // splits per (b,n2); one WAVE per split
#define CHW  (SP_ / NSPLIT) // 32 indices per wave-split
#define NP   (CHW / 2)      // 16 index-pairs per wave
#define SPG  (NSPLIT / 4)   // split-groups per pair (4 waves/block)

// Kernel 1: per (b, n2, split) partial attention. One wave per split, no LDS,
// no barriers. Half-wave (32 lanes) x float4 granularity: every load
// instruction fetches TWO distinct 512B KV rows (1KB dense).
//  - Phase 1: half hw handles index 2*pr+hw; lane reads dims 4sl..4sl+3,
//    4-head dot, head-interleaved butterfly within the half (7 shuffles per
//    2 indices) -> lane holds score for head (lane&3).
//  - Softmax in registers; cross-half max/sum via 2 xor-32 shuffles.
//  - Phase 2: same half-wave row ownership; p broadcast via 4 shuffles/pair;
//    16 accumulators (4 heads x float4); 16-shuffle cross-half combine.
__global__ __launch_bounds__(256, 4) void attn_part(
    const float* __restrict__ q, const float* __restrict__ key,
    const float* __restrict__ value, const int* __restrict__ sidx,
    const float* __restrict__ scale_p, float* __restrict__ ws_o,
    float2* __restrict__ ws_ml)
{
    const int blk   = blockIdx.x;
    const int tid   = threadIdx.x;
    const int lane  = tid & 63;
    const int w     = tid >> 6;
    const int hw    = lane >> 5;              // half id (0/1)
    const int sl    = lane & 31;              // sub-lane in half
    const int pair  = blk / SPG;              // b*N2 + n2
    const int split = (blk % SPG) * 4 + w;    // 0..63
    const int n2    = pair & (N2_ - 1);
    const int b     = pair >> 3;

    const float scale = scale_p[0];

    // q for 4 heads, dims 4sl..4sl+3, pre-scaled
    const float* qb = q + (size_t)(pair * G_) * D_ + (sl << 2);
    float4 q4[G_];
#pragma unroll
    for (int h = 0; h < G_; ++h) {
        float4 t = *(const float4*)(qb + h * D_);
        q4[h] = make_float4(t.x * scale, t.y * scale, t.z * scale, t.w * scale);
    }

    // this split's 32 indices, one per lane slot
    const int* idx_base = sidx + (size_t)pair * SP_ + split * CHW;
    const int myidx = idx_base[lane & (CHW - 1)];

    const size_t kvbase = (size_t)b * ((size_t)S2_ * N2_ * D_) + (size_t)n2 * D_;
    const float* kb = key   + kvbase + (sl << 2);
    const float* vb = value + kvbase + (sl << 2);

    // ---- Phase 1: scores. Half hw owns index 2*pr+hw. ----
    int   idx2[NP];
    float x[NP];
#pragma unroll
    for (int pr = 0; pr < NP; ++pr) {
        const int s2 = __shfl(myidx, 2 * pr + hw);
        idx2[pr] = s2;
        const float4 kv = *(const float4*)(kb + (size_t)s2 * (N2_ * D_));
        float p0 = q4[0].x * kv.x + q4[0].y * kv.y + q4[0].z * kv.z + q4[0].w * kv.w;
        float p1 = q4[1].x * kv.x + q4[1].y * kv.y + q4[1].z * kv.z + q4[1].w * kv.w;
        float p2 = q4[2].x * kv.x + q4[2].y * kv.y + q4[2].z * kv.z + q4[2].w * kv.w;
        float p3 = q4[3].x * kv.x + q4[3].y * kv.y + q4[3].z * kv.z + q4[3].w * kv.w;
        // head-interleaved butterfly within the 32-lane half (offsets 1..16)
        float a  = (lane & 1) ? p1 : p0;
        float sb = (lane & 1) ? p0 : p1;
        a += __shfl_xor(sb, 1);
        float c  = (lane & 1) ? p3 : p2;
        float sd = (lane & 1) ? p2 : p3;
        c += __shfl_xor(sd, 1);
        float e  = (lane & 2) ? c : a;
        float sf = (lane & 2) ? a : c;
        e += __shfl_xor(sf, 2);
        e += __shfl_xor(e, 4);
        e += __shfl_xor(e, 8);
        e += __shfl_xor(e, 16);
        x[pr] = e;   // score[head lane&3][index 2*pr+hw], bcast in half
    }

    // ---- softmax in registers (head = lane&3), cross-half via xor-32 ----
    float m = x[0];
#pragma unroll
    for (int pr = 1; pr < NP; ++pr) m = fmaxf(m, x[pr]);
    m = fmaxf(m, __shfl_xor(m, 32));
    float sum = 0.f;
#pragma unroll
    for (int pr = 0; pr < NP; ++pr) {
        x[pr] = __expf(x[pr] - m);
        sum += x[pr];
    }
    sum += __shfl_xor(sum, 32);

    // ---- Phase 2: PV. Half hw owns index 2*pr+hw; lane dims 4sl..4sl+3 ----
    float4 acc0 = make_float4(0.f, 0.f, 0.f, 0.f);
    float4 acc1 = acc0, acc2 = acc0, acc3 = acc0;
#pragma unroll
    for (int pr = 0; pr < NP; ++pr) {
        const float4 vv = *(const float4*)(vb + (size_t)idx2[pr] * (N2_ * D_));
        const int base = lane & ~3;
        const float p0 = __shfl(x[pr], base | 0);
        const float p1 = __shfl(x[pr], base | 1);
        const float p2 = __shfl(x[pr], base | 2);
        const float p3 = __shfl(x[pr], base | 3);
        acc0.x += p0 * vv.x; acc0.y += p0 * vv.y; acc0.z += p0 * vv.z; acc0.w += p0 * vv.w;
        acc1.x += p1 * vv.x; acc1.y += p1 * vv.y; acc1.z += p1 * vv.z; acc1.w += p1 * vv.w;
        acc2.x += p2 * vv.x; acc2.y += p2 * vv.y; acc2.z += p2 * vv.z; acc2.w += p2 * vv.w;
        acc3.x += p3 * vv.x; acc3.y += p3 * vv.y; acc3.z += p3 * vv.z; acc3.w += p3 * vv.w;
    }

    // cross-half combine (each half summed its own 16 indices)
    acc0.x += __shfl_xor(acc0.x, 32); acc0.y += __shfl_xor(acc0.y, 32);
    acc0.z += __shfl_xor(acc0.z, 32); acc0.w += __shfl_xor(acc0.w, 32);
    acc1.x += __shfl_xor(acc1.x, 32); acc1.y += __shfl_xor(acc1.y, 32);
    acc1.z += __shfl_xor(acc1.z, 32); acc1.w += __shfl_xor(acc1.w, 32);
    acc2.x += __shfl_xor(acc2.x, 32); acc2.y += __shfl_xor(acc2.y, 32);
    acc2.z += __shfl_xor(acc2.z, 32); acc2.w += __shfl_xor(acc2.w, 32);
    acc3.x += __shfl_xor(acc3.x, 32); acc3.y += __shfl_xor(acc3.y, 32);
    acc3.z += __shfl_xor(acc3.z, 32); acc3.w += __shfl_xor(acc3.w, 32);

    // ---- write partials: half hw writes heads 2hw, 2hw+1 (static select) ----
    const float4 w0 = hw ? acc2 : acc0;
    const float4 w1 = hw ? acc3 : acc1;
    const int h0 = hw << 1;
    float* wo = ws_o + ((size_t)(pair * G_ + h0) * NSPLIT + split) * D_ + (sl << 2);
    *(float4*)(wo)                        = w0;
    *(float4*)(wo + (size_t)NSPLIT * D_)  = w1;
    if (lane < G_)
        ws_ml[((size_t)pair * G_ + lane) * NSPLIT + split] = make_float2(m, sum);
}

// Kernel 2: combine NSPLIT partials. One block per (pair, head), 128 threads
// (thread = dim). Standard log-sum-exp merge.
__global__ __launch_bounds__(128) void attn_comb(
    const float* __restrict__ ws_o, const float2* __restrict__ ws_ml,
    float* __restrict__ out)
{
    const int ph  = blockIdx.x;       // pair*G + h
    const int tid = threadIdx.x;      // dim

    __shared__ float2 sml[NSPLIT];
    if (tid < NSPLIT) sml[tid] = ws_ml[(size_t)ph * NSPLIT + tid];
    __syncthreads();

    float M = -1e30f;
#pragma unroll
    for (int s = 0; s < NSPLIT; ++s)
        M = fmaxf(M, sml[s].x);

    float L = 0.f, acc = 0.f;
    const float* wo = ws_o + (size_t)ph * NSPLIT * D_ + tid;
#pragma unroll
    for (int s = 0; s < NSPLIT; ++s) {
        const float2 mlv = sml[s];
        const float wgt  = __expf(mlv.x - M);
        L   += wgt * mlv.y;
        acc += wgt * wo[(size_t)s * D_];
    }
    out[(size_t)ph * D_ + tid] = acc / L;
}

extern "C" void kernel_launch(void* const* d_in, const int* in_sizes, int n_in,
                              void* d_out, int out_size, void* d_ws, size_t ws_size,
                              hipStream_t stream)
{
    const float* q  = (const float*)d_in[0];
    const float* k  = (const float*)d_in[1];
    const float* v  = (const float*)d_in[2];
    const int*   si = (const int*)d_in[3];
    const float* sc = (const float*)d_in[4];
    float* out = (float*)d_out;

    float*  ws_o  = (float*)d_ws;                                    // 8 MB
    float2* ws_ml = (float2*)(ws_o + (size_t)B_ * N2_ * G_ * NSPLIT * D_);

    attn_part<<<B_ * N2_ * SPG, 256, 0, stream>>>(q, k, v, si, sc, ws_o, ws_ml);
    attn_comb<<<B_ * N2_ * G_, 128, 0, stream>>>(ws_o, ws_ml, out);
}